// Round 2
// baseline (391.686 us; speedup 1.0000x reference)
//
#include <hip/hip_runtime.h>

#define N_TOTAL 150000
#define DIM 128
#define NNZ_E 1500000
#define NBUCK 256
#define DPB 586                 // dests per bucket: 256*586 = 150016 >= 150000
#define EPB2 2048               // edges per fused phase-A block (emits 2 entries each)
#define A2_BLOCKS ((NNZ_E + EPB2 - 1) / EPB2)   // 733

typedef unsigned long long u64;

// ---------- bf16 pack/unpack (RNE) ----------
__device__ __forceinline__ unsigned pack_bf16_bits(unsigned ua, unsigned ub) {
    ua = (ua + 0x7FFFu + ((ua >> 16) & 1u)) >> 16;
    ub = (ub + 0x7FFFu + ((ub >> 16) & 1u)) >> 16;
    return ua | (ub << 16);
}
__device__ __forceinline__ unsigned pack_bf16(float a, float b) {
    return pack_bf16_bits(__float_as_uint(a), __float_as_uint(b));
}
__device__ __forceinline__ float2 unpack_bf16(unsigned u) {
    return make_float2(__uint_as_float(u << 16), __uint_as_float(u & 0xFFFF0000u));
}
__device__ __forceinline__ float rdlane_f(float x, int l) {
    return __uint_as_float((unsigned)__builtin_amdgcn_readlane((int)__float_as_uint(x), l));
}

// ---------- ego fp32 -> packed bf16 (nontemporal via u64 lanes) ----------
__global__ __launch_bounds__(256) void conv_bf16(const float* __restrict__ in,
                                                 uint* __restrict__ outp) {
    int i = blockIdx.x * 256 + threadIdx.x;      // exactly N*D/8 threads
    const u64* in8 = (const u64*)in;             // one u64 = 2 floats
    u64 w0 = __builtin_nontemporal_load(&in8[4 * i + 0]);
    u64 w1 = __builtin_nontemporal_load(&in8[4 * i + 1]);
    u64 w2 = __builtin_nontemporal_load(&in8[4 * i + 2]);
    u64 w3 = __builtin_nontemporal_load(&in8[4 * i + 3]);
    uint4 o;
    o.x = pack_bf16_bits((unsigned)w0, (unsigned)(w0 >> 32));
    o.y = pack_bf16_bits((unsigned)w1, (unsigned)(w1 >> 32));
    o.z = pack_bf16_bits((unsigned)w2, (unsigned)(w2 >> 32));
    o.w = pack_bf16_bits((unsigned)w3, (unsigned)(w3 >> 32));
    ((uint4*)outp)[i] = o;
}

// ---------- coarse histogram: 2x256 buckets, LDS-aggregated ----------
__global__ __launch_bounds__(256) void coarse_hist(const int* __restrict__ rows,
                                                   const int* __restrict__ cols,
                                                   int* __restrict__ cnt1,
                                                   int* __restrict__ cnt2) {
    __shared__ int h[512];
    int t = threadIdx.x;
    h[t] = 0; h[t + 256] = 0;
    __syncthreads();
    int stride = gridDim.x * blockDim.x;
    for (int e = blockIdx.x * blockDim.x + t; e < NNZ_E; e += stride) {
        atomicAdd(&h[cols[e] / DPB], 1);          // pass-1 dest = col
        atomicAdd(&h[256 + rows[e] / DPB], 1);    // pass-2 dest = row
    }
    __syncthreads();
    if (h[t]) atomicAdd(&cnt1[t], h[t]);
    if (h[t + 256]) atomicAdd(&cnt2[t], h[t + 256]);
}

// ---------- scan 512 bucket counts -> slab bases sb[513]; zero cursors ----------
__global__ __launch_bounds__(256) void scan_buckets(const int* __restrict__ cnt,
                                                    int* __restrict__ sb,
                                                    int* __restrict__ gc) {
    __shared__ int buf[256];
    int t = threadIdx.x;
    int v = cnt[t]; buf[t] = v; __syncthreads();
    for (int o = 1; o < 256; o <<= 1) {
        int a = (t >= o) ? buf[t - o] : 0; __syncthreads();
        buf[t] += a; __syncthreads();
    }
    sb[t] = buf[t] - v;               // pass-1 region: [0, NNZ)
    __syncthreads();
    int v2 = cnt[256 + t]; buf[t] = v2; __syncthreads();
    for (int o = 1; o < 256; o <<= 1) {
        int a = (t >= o) ? buf[t - o] : 0; __syncthreads();
        buf[t] += a; __syncthreads();
    }
    sb[256 + t] = NNZ_E + buf[t] - v2;  // pass-2 region: [NNZ, 2*NNZ)
    if (t == 255) sb[512] = 2 * NNZ_E;
    gc[t] = 0; gc[256 + t] = 0;
}

// ---------- fused phase A: bin 2048 edges -> 4096 entries over 512 buckets ----------
__global__ __launch_bounds__(256) void phaseA_fused(const int* __restrict__ rows,
                                                    const int* __restrict__ cols,
                                                    const float* __restrict__ vals,
                                                    const int* __restrict__ slabBase,
                                                    int* __restrict__ gCur,
                                                    uint2* __restrict__ slab) {
    __shared__ uint2 sortedL[2 * EPB2];          // 32 KB
    __shared__ unsigned short bktL[2 * EPB2];    // 8 KB
    __shared__ int cnt[512], off[512], cur[512], gbase[512];   // 8 KB
    __shared__ int part[256];                    // 1 KB
    __shared__ int totE;
    int t = threadIdx.x;
    int base = blockIdx.x * EPB2;
    cnt[t] = 0; cnt[t + 256] = 0;
    __syncthreads();

    uint2 eA[8], eB[8];
    short bA[8], bB[8];
    #pragma unroll
    for (int j = 0; j < 8; j++) {
        int e = base + j * 256 + t;
        if (e < NNZ_E) {
            int r = rows[e], c = cols[e];
            unsigned v = __float_as_uint(vals[e]);
            int b1 = c / DPB, dl1 = c - b1 * DPB;     // pass-1 dest = col, src = row
            int b2 = r / DPB, dl2 = r - b2 * DPB;     // pass-2 dest = row, src = col
            bA[j] = (short)b1;
            eA[j].x = ((unsigned)dl1 << 18) | (unsigned)r;
            eA[j].y = v;
            bB[j] = (short)(256 + b2);
            eB[j].x = ((unsigned)dl2 << 18) | (unsigned)c;
            eB[j].y = v;
            atomicAdd(&cnt[b1], 1);
            atomicAdd(&cnt[256 + b2], 1);
        } else { bA[j] = -1; bB[j] = -1; }
    }
    __syncthreads();
    // scan 512 counts (2 per thread) -> exclusive off/cur
    int c0 = cnt[2 * t], c1 = cnt[2 * t + 1];
    int ps = c0 + c1;
    part[t] = ps; __syncthreads();
    for (int o = 1; o < 256; o <<= 1) {
        int a = (t >= o) ? part[t - o] : 0; __syncthreads();
        part[t] += a; __syncthreads();
    }
    int bs = part[t] - ps;
    off[2 * t] = bs;          cur[2 * t] = bs;
    off[2 * t + 1] = bs + c0; cur[2 * t + 1] = bs + c0;
    if (t == 255) totE = part[255];
    __syncthreads();
    // bucket-sorted scatter into LDS (both entries per edge)
    #pragma unroll
    for (int j = 0; j < 8; j++) {
        if (bA[j] >= 0) {
            int p = atomicAdd(&cur[(int)bA[j]], 1);
            sortedL[p] = eA[j]; bktL[p] = (unsigned short)bA[j];
            p = atomicAdd(&cur[(int)bB[j]], 1);
            sortedL[p] = eB[j]; bktL[p] = (unsigned short)bB[j];
        }
    }
    __syncthreads();
    // reserve global slab space, one atomic per non-empty bucket
    for (int b = t; b < 512; b += 256) {
        int n = cnt[b];
        if (n > 0) gbase[b] = atomicAdd(&gCur[b], n);
    }
    __syncthreads();
    int nE = totE;
    for (int i = t; i < nE; i += 256) {
        int b = bktL[i];
        slab[slabBase[b] + gbase[b] + (i - off[b])] = sortedL[i];
    }
}

// ---------- phase B: per-bucket exact sort + offs write + (src,val) emit ----------
__global__ __launch_bounds__(256) void phaseB(const uint2* __restrict__ slab,
                                              const int* __restrict__ slabBase,
                                              int* __restrict__ offs1,
                                              int* __restrict__ offs2,
                                              uint2* __restrict__ sorted) {
    __shared__ int cnt[DPB], sc[DPB], cur[DPB], part[256];
    int b = blockIdx.x, t = threadIdx.x;
    int sb = slabBase[b], se = slabBase[b + 1];
    int n = se - sb;
    for (int d = t; d < DPB; d += 256) cnt[d] = 0;
    __syncthreads();
    for (int i = t; i < n; i += 256)
        atomicAdd(&cnt[slab[sb + i].x >> 18], 1);
    __syncthreads();
    int d0 = t * 3;
    int c0 = (d0     < DPB) ? cnt[d0]     : 0;
    int c1 = (d0 + 1 < DPB) ? cnt[d0 + 1] : 0;
    int c2 = (d0 + 2 < DPB) ? cnt[d0 + 2] : 0;
    int ps = c0 + c1 + c2;
    part[t] = ps;
    __syncthreads();
    for (int o = 1; o < 256; o <<= 1) {
        int a = (t >= o) ? part[t - o] : 0; __syncthreads();
        part[t] += a; __syncthreads();
    }
    int bs = part[t] - ps;
    if (d0     < DPB) { sc[d0]     = bs;           cur[d0]     = bs; }
    if (d0 + 1 < DPB) { sc[d0 + 1] = bs + c0;      cur[d0 + 1] = bs + c0; }
    if (d0 + 2 < DPB) { sc[d0 + 2] = bs + c0 + c1; cur[d0 + 2] = bs + c0 + c1; }
    __syncthreads();
    int destBase = (b & 255) * DPB;
    int* offs = (b < NBUCK) ? offs1 : offs2;
    for (int d = t; d < DPB; d += 256) {
        int dd = destBase + d;
        if (dd <= N_TOTAL) offs[dd] = sb + sc[d];   // absolute index into sorted[]
    }
    for (int i = t; i < n; i += 256) {
        uint2 e = slab[sb + i];
        int dl = e.x >> 18;
        int p = atomicAdd(&cur[dl], 1);
        sorted[sb + p] = make_uint2(e.x & 0x3FFFF, e.y);
    }
}

// ---------- gather 1: bf16 in, bf16 out, readlane-scalarized ----------
__global__ __launch_bounds__(256) void gather1(const uint* __restrict__ srcBf,
                                               const int* __restrict__ offs,
                                               const uint2* __restrict__ edges,
                                               uint* __restrict__ dstBf) {
    int gid = blockIdx.x * 256 + threadIdx.x;
    int row = gid >> 6, lane = gid & 63;
    if (row >= N_TOTAL) return;
    int beg = offs[row], end = offs[row + 1];
    int n = end - beg;
    uint2 meta = make_uint2(0u, 0u);
    if (lane < n) {
        u64 w = __builtin_nontemporal_load((const u64*)(edges + beg + lane));
        meta.x = (unsigned)w;
        meta.y = (unsigned)(w >> 32);
    }
    float2 a0 = make_float2(0.f, 0.f), a1 = make_float2(0.f, 0.f);
    float2 a2 = make_float2(0.f, 0.f), a3 = make_float2(0.f, 0.f);
    int nin = n < 64 ? n : 64;
    int i = 0;
    for (; i + 4 <= nin; i += 4) {
        int s0 = __builtin_amdgcn_readlane((int)meta.x, i);
        int s1 = __builtin_amdgcn_readlane((int)meta.x, i + 1);
        int s2 = __builtin_amdgcn_readlane((int)meta.x, i + 2);
        int s3 = __builtin_amdgcn_readlane((int)meta.x, i + 3);
        unsigned x0 = srcBf[(((size_t)s0) << 6) + lane];
        unsigned x1 = srcBf[(((size_t)s1) << 6) + lane];
        unsigned x2 = srcBf[(((size_t)s2) << 6) + lane];
        unsigned x3 = srcBf[(((size_t)s3) << 6) + lane];
        float v0 = rdlane_f(__uint_as_float(meta.y), i);
        float v1 = rdlane_f(__uint_as_float(meta.y), i + 1);
        float v2 = rdlane_f(__uint_as_float(meta.y), i + 2);
        float v3 = rdlane_f(__uint_as_float(meta.y), i + 3);
        float2 u;
        u = unpack_bf16(x0); a0.x += v0 * u.x; a0.y += v0 * u.y;
        u = unpack_bf16(x1); a1.x += v1 * u.x; a1.y += v1 * u.y;
        u = unpack_bf16(x2); a2.x += v2 * u.x; a2.y += v2 * u.y;
        u = unpack_bf16(x3); a3.x += v3 * u.x; a3.y += v3 * u.y;
    }
    for (; i < nin; i++) {
        int s = __builtin_amdgcn_readlane((int)meta.x, i);
        float v = rdlane_f(__uint_as_float(meta.y), i);
        float2 u = unpack_bf16(srcBf[(((size_t)s) << 6) + lane]);
        a0.x += v * u.x; a0.y += v * u.y;
    }
    for (int k = 64; k < n; k++) {       // statistically never (Poisson(10))
        uint2 e = edges[beg + k];
        float v = __uint_as_float(e.y);
        float2 u = unpack_bf16(srcBf[(((size_t)e.x) << 6) + lane]);
        a0.x += v * u.x; a0.y += v * u.y;
    }
    float2 acc = make_float2(a0.x + a1.x + a2.x + a3.x, a0.y + a1.y + a2.y + a3.y);
    dstBf[(size_t)row * 64 + lane] = pack_bf16(acc.x, acc.y);
}

// ---------- gather 2 + LN + residual: bf16 in, fp32 out, readlane-scalarized ----------
__global__ __launch_bounds__(256) void gather2_ln(const uint* __restrict__ hBf,
                                                  const int* __restrict__ offs,
                                                  const uint2* __restrict__ edges,
                                                  const uint* __restrict__ egoBf,
                                                  const float* __restrict__ gamma,
                                                  const float* __restrict__ beta,
                                                  float* __restrict__ out) {
    int gid = blockIdx.x * 256 + threadIdx.x;
    int row = gid >> 6, lane = gid & 63;
    if (row >= N_TOTAL) return;
    int beg = offs[row], end = offs[row + 1];
    int n = end - beg;
    uint2 meta = make_uint2(0u, 0u);
    if (lane < n) {
        u64 w = __builtin_nontemporal_load((const u64*)(edges + beg + lane));
        meta.x = (unsigned)w;
        meta.y = (unsigned)(w >> 32);
    }
    float2 a0 = make_float2(0.f, 0.f), a1 = make_float2(0.f, 0.f);
    float2 a2 = make_float2(0.f, 0.f), a3 = make_float2(0.f, 0.f);
    int nin = n < 64 ? n : 64;
    int i = 0;
    for (; i + 4 <= nin; i += 4) {
        int s0 = __builtin_amdgcn_readlane((int)meta.x, i);
        int s1 = __builtin_amdgcn_readlane((int)meta.x, i + 1);
        int s2 = __builtin_amdgcn_readlane((int)meta.x, i + 2);
        int s3 = __builtin_amdgcn_readlane((int)meta.x, i + 3);
        unsigned x0 = hBf[(((size_t)s0) << 6) + lane];
        unsigned x1 = hBf[(((size_t)s1) << 6) + lane];
        unsigned x2 = hBf[(((size_t)s2) << 6) + lane];
        unsigned x3 = hBf[(((size_t)s3) << 6) + lane];
        float v0 = rdlane_f(__uint_as_float(meta.y), i);
        float v1 = rdlane_f(__uint_as_float(meta.y), i + 1);
        float v2 = rdlane_f(__uint_as_float(meta.y), i + 2);
        float v3 = rdlane_f(__uint_as_float(meta.y), i + 3);
        float2 u;
        u = unpack_bf16(x0); a0.x += v0 * u.x; a0.y += v0 * u.y;
        u = unpack_bf16(x1); a1.x += v1 * u.x; a1.y += v1 * u.y;
        u = unpack_bf16(x2); a2.x += v2 * u.x; a2.y += v2 * u.y;
        u = unpack_bf16(x3); a3.x += v3 * u.x; a3.y += v3 * u.y;
    }
    for (; i < nin; i++) {
        int s = __builtin_amdgcn_readlane((int)meta.x, i);
        float v = rdlane_f(__uint_as_float(meta.y), i);
        float2 u = unpack_bf16(hBf[(((size_t)s) << 6) + lane]);
        a0.x += v * u.x; a0.y += v * u.y;
    }
    for (int k = 64; k < n; k++) {
        uint2 e = edges[beg + k];
        float v = __uint_as_float(e.y);
        float2 u = unpack_bf16(hBf[(((size_t)e.x) << 6) + lane]);
        a0.x += v * u.x; a0.y += v * u.y;
    }
    float2 acc = make_float2(a0.x + a1.x + a2.x + a3.x, a0.y + a1.y + a2.y + a3.y);
    float s = acc.x + acc.y;
    float sq = acc.x * acc.x + acc.y * acc.y;
    #pragma unroll
    for (int o = 1; o <= 16; o <<= 1) {
        s  += __shfl_xor(s, o, 64);
        sq += __shfl_xor(sq, o, 64);
    }
    // lanes 0 and 32 hold the two half-sums -> finish with scalar readlanes
    float sT  = rdlane_f(s, 0)  + rdlane_f(s, 32);
    float sqT = rdlane_f(sq, 0) + rdlane_f(sq, 32);
    float mu = sT * (1.0f / DIM);
    float var = sqT * (1.0f / DIM) - mu * mu;
    float rs = rsqrtf(var + 1e-5f);
    float2 g  = ((const float2*)gamma)[lane];
    float2 bb = ((const float2*)beta)[lane];
    unsigned egoW = __builtin_nontemporal_load(&egoBf[(size_t)row * 64 + lane]);
    float2 e2 = unpack_bf16(egoW);
    float2 o2;
    o2.x = (acc.x - mu) * rs * g.x + bb.x + e2.x;
    o2.y = (acc.y - mu) * rs * g.y + bb.y + e2.y;
    u64 ow = (u64)__float_as_uint(o2.x) | ((u64)__float_as_uint(o2.y) << 32);
    __builtin_nontemporal_store(ow, (u64*)out + (size_t)row * 64 + lane);
}

// ---------- fallback: atomic scatter path (ws too small) ----------
__device__ __forceinline__ void atomic_add_f32(float* p, float v) {
    __hip_atomic_fetch_add(p, v, __ATOMIC_RELAXED, __HIP_MEMORY_SCOPE_AGENT);
}
__global__ void scatter_kernel(const float* __restrict__ src, const float* __restrict__ vals,
                               const int* __restrict__ gidx, const int* __restrict__ sidx,
                               float* __restrict__ dst, int nnz) {
    int gid = blockIdx.x * blockDim.x + threadIdx.x;
    int e = gid >> 5, lane = gid & 31;
    if (e >= nnz) return;
    float v = vals[e];
    float4 x = ((const float4*)(src + (size_t)gidx[e] * DIM))[lane];
    float* d = dst + (size_t)sidx[e] * DIM + lane * 4;
    atomic_add_f32(d + 0, v * x.x); atomic_add_f32(d + 1, v * x.y);
    atomic_add_f32(d + 2, v * x.z); atomic_add_f32(d + 3, v * x.w);
}
__global__ void ln_residual_kernel(const float* __restrict__ h2, const float* __restrict__ ego,
                                   const float* __restrict__ gamma, const float* __restrict__ beta,
                                   float* __restrict__ out, int nrows) {
    int gid = blockIdx.x * blockDim.x + threadIdx.x;
    int row = gid >> 6, lane = gid & 63;
    if (row >= nrows) return;
    float2 x = ((const float2*)(h2 + (size_t)row * DIM))[lane];
    float s = x.x + x.y, sq = x.x * x.x + x.y * x.y;
    #pragma unroll
    for (int o = 32; o > 0; o >>= 1) { s += __shfl_xor(s, o, 64); sq += __shfl_xor(sq, o, 64); }
    float mu = s * (1.0f / DIM), var = sq * (1.0f / DIM) - mu * mu;
    float rs = rsqrtf(var + 1e-5f);
    float2 eg = ((const float2*)(ego + (size_t)row * DIM))[lane];
    float2 g = ((const float2*)gamma)[lane], b = ((const float2*)beta)[lane];
    float2 o2;
    o2.x = (x.x - mu) * rs * g.x + b.x + eg.x;
    o2.y = (x.y - mu) * rs * g.y + b.y + eg.y;
    ((float2*)(out + (size_t)row * DIM))[lane] = o2;
}

// ---------- launch ----------
extern "C" void kernel_launch(void* const* d_in, const int* in_sizes, int n_in,
                              void* d_out, int out_size, void* d_ws, size_t ws_size,
                              hipStream_t stream) {
    const float* ego   = (const float*)d_in[0];
    const float* vals  = (const float*)d_in[1];
    const float* gamma = (const float*)d_in[2];
    const float* beta  = (const float*)d_in[3];
    const int*   rows  = (const int*)d_in[4];
    const int*   cols  = (const int*)d_in[5];
    float* out = (float*)d_out;

    const size_t EGO_BF_B = (size_t)N_TOTAL * DIM * 2;               // 38.4 MB
    const size_t SLAB_B   = (size_t)2 * NNZ_E * sizeof(uint2);       // 24 MB
    const size_t H_BF_B   = (size_t)N_TOTAL * DIM * 2;               // 38.4 MB
    const size_t REGION_B = (SLAB_B > H_BF_B) ? SLAB_B : H_BF_B;     // hBf aliases dead slab
    const size_t SORT_B   = (size_t)2 * NNZ_E * sizeof(uint2);       // 24 MB
    const size_t OFFS_B   = ((size_t)N_TOTAL + 16) * sizeof(int);    // ~0.6 MB each
    const size_t SMALL    = 16384;
    const size_t REQ = EGO_BF_B + REGION_B + SORT_B + 2 * OFFS_B + SMALL;   // ~102 MB
    const size_t H_FP32_B = (size_t)N_TOTAL * DIM * sizeof(float);   // fallback: 76.8 MB

    char* w = (char*)d_ws;
    uint* egoBf   = (uint*)w;   w += EGO_BF_B;
    char* region  = w;          w += REGION_B;
    uint2* slab   = (uint2*)region;      // live: phaseA_fused -> phaseB
    uint* hBf     = (uint*)region;       // live: gather1 -> gather2 (slab dead by then)
    uint2* sorted = (uint2*)w;  w += SORT_B;
    int* offs1    = (int*)w;    w += OFFS_B;
    int* offs2    = (int*)w;    w += OFFS_B;
    int* cntArr   = (int*)w;    w += 512 * sizeof(int);
    int* sb       = (int*)w;    w += 516 * sizeof(int);
    int* gc       = (int*)w;    w += 512 * sizeof(int);

    if (ws_size >= REQ) {
        (void)hipMemsetAsync(cntArr, 0, 512 * sizeof(int), stream);
        conv_bf16<<<(N_TOTAL * DIM / 8) / 256, 256, 0, stream>>>(ego, egoBf);
        coarse_hist<<<512, 256, 0, stream>>>(rows, cols, cntArr, cntArr + 256);
        scan_buckets<<<1, 256, 0, stream>>>(cntArr, sb, gc);
        phaseA_fused<<<A2_BLOCKS, 256, 0, stream>>>(rows, cols, vals, sb, gc, slab);
        phaseB<<<512, 256, 0, stream>>>(slab, sb, offs1, offs2, sorted);

        int ggrid = (N_TOTAL * 64) / 256;   // 37500
        gather1<<<ggrid, 256, 0, stream>>>(egoBf, offs1, sorted, hBf);
        gather2_ln<<<ggrid, 256, 0, stream>>>(hBf, offs2, sorted, egoBf, gamma, beta, out);
    } else {
        float* h = (float*)d_ws;            // fallback: fp32 h at ws start
        (void)hipMemsetAsync(h, 0, H_FP32_B, stream);
        (void)hipMemsetAsync(out, 0, H_FP32_B, stream);
        long total = (long)NNZ_E * 32;
        int grid = (int)((total + 255) / 256);
        scatter_kernel<<<grid, 256, 0, stream>>>(ego, vals, rows, cols, h, NNZ_E);
        scatter_kernel<<<grid, 256, 0, stream>>>(h, vals, cols, rows, out, NNZ_E);
        int lngrid = (N_TOTAL * 64 + 255) / 256;
        ln_residual_kernel<<<lngrid, 256, 0, stream>>>(out, ego, gamma, beta, out, N_TOTAL);
    }
}

// Round 3
// 369.755 us; speedup vs baseline: 1.0593x; 1.0593x over previous
//
#include <hip/hip_runtime.h>

#define N_TOTAL 150000
#define DIM 128
#define NNZ_E 1500000
#define NBUCK 256
#define DPB 586                 // dests per bucket: 256*586 = 150016 >= 150000
#define EPB2 2048               // edges per fused phase-A block (emits 2 entries each)
#define A2_BLOCKS ((NNZ_E + EPB2 - 1) / EPB2)   // 733

typedef unsigned long long u64;
typedef unsigned uvec16 __attribute__((ext_vector_type(16)));
typedef unsigned uvec2  __attribute__((ext_vector_type(2)));

// ---------- bf16 pack/unpack (RNE) ----------
__device__ __forceinline__ unsigned pack_bf16_bits(unsigned ua, unsigned ub) {
    ua = (ua + 0x7FFFu + ((ua >> 16) & 1u)) >> 16;
    ub = (ub + 0x7FFFu + ((ub >> 16) & 1u)) >> 16;
    return ua | (ub << 16);
}
__device__ __forceinline__ unsigned pack_bf16(float a, float b) {
    return pack_bf16_bits(__float_as_uint(a), __float_as_uint(b));
}
__device__ __forceinline__ float2 unpack_bf16(unsigned u) {
    return make_float2(__uint_as_float(u << 16), __uint_as_float(u & 0xFFFF0000u));
}
__device__ __forceinline__ float rdlane_f(float x, int l) {
    return __uint_as_float((unsigned)__builtin_amdgcn_readlane((int)__float_as_uint(x), l));
}

// ---------- scalar-pipe metadata loads (wave-uniform) ----------
__device__ __forceinline__ void sload_pair(uvec16 &a, uvec16 &b, const void* p) {
    asm volatile("s_load_dwordx16 %0, %2, 0x0\n\t"
                 "s_load_dwordx16 %1, %2, 0x40\n\t"
                 "s_waitcnt lgkmcnt(0)"
                 : "=&s"(a), "=&s"(b) : "s"(p) : "memory");
}
__device__ __forceinline__ void sload_be(uvec2 &r, const void* p) {
    asm volatile("s_load_dwordx2 %0, %1, 0x0\n\t"
                 "s_waitcnt lgkmcnt(0)"
                 : "=&s"(r) : "s"(p) : "memory");
}

// process 8 edges from an SGPR chunk; lim = valid count (scalar).
// Speculative slots: sx clamped scalar-side, vv zeroed via s_cselect.
__device__ __forceinline__ void chunk8(const uvec16 &m, int lim, int lane,
                                       const uint* __restrict__ srcBf,
                                       float &ax, float &ay, float &bx, float &by) {
    #pragma unroll
    for (int j = 0; j < 8; j++) {
        unsigned sx = m[2 * j] & 0x3FFFFu;
        sx = (sx < (unsigned)N_TOTAL) ? sx : 0u;
        float vv = (j < lim) ? __uint_as_float(m[2 * j + 1]) : 0.0f;
        const uint* p = srcBf + ((size_t)sx << 6);   // uniform base -> saddr load
        float2 uu = unpack_bf16(p[lane]);
        if (j & 1) { bx += vv * uu.x; by += vv * uu.y; }
        else       { ax += vv * uu.x; ay += vv * uu.y; }
    }
}

// ---------- ego fp32 -> packed bf16 (nontemporal via u64 lanes) ----------
__global__ __launch_bounds__(256) void conv_bf16(const float* __restrict__ in,
                                                 uint* __restrict__ outp) {
    int i = blockIdx.x * 256 + threadIdx.x;      // exactly N*D/8 threads
    const u64* in8 = (const u64*)in;             // one u64 = 2 floats
    u64 w0 = __builtin_nontemporal_load(&in8[4 * i + 0]);
    u64 w1 = __builtin_nontemporal_load(&in8[4 * i + 1]);
    u64 w2 = __builtin_nontemporal_load(&in8[4 * i + 2]);
    u64 w3 = __builtin_nontemporal_load(&in8[4 * i + 3]);
    uint4 o;
    o.x = pack_bf16_bits((unsigned)w0, (unsigned)(w0 >> 32));
    o.y = pack_bf16_bits((unsigned)w1, (unsigned)(w1 >> 32));
    o.z = pack_bf16_bits((unsigned)w2, (unsigned)(w2 >> 32));
    o.w = pack_bf16_bits((unsigned)w3, (unsigned)(w3 >> 32));
    ((uint4*)outp)[i] = o;
}

// ---------- coarse histogram: 2x256 buckets, LDS-aggregated ----------
__global__ __launch_bounds__(256) void coarse_hist(const int* __restrict__ rows,
                                                   const int* __restrict__ cols,
                                                   int* __restrict__ cnt1,
                                                   int* __restrict__ cnt2) {
    __shared__ int h[512];
    int t = threadIdx.x;
    h[t] = 0; h[t + 256] = 0;
    __syncthreads();
    int stride = gridDim.x * blockDim.x;
    for (int e = blockIdx.x * blockDim.x + t; e < NNZ_E; e += stride) {
        atomicAdd(&h[cols[e] / DPB], 1);          // pass-1 dest = col
        atomicAdd(&h[256 + rows[e] / DPB], 1);    // pass-2 dest = row
    }
    __syncthreads();
    if (h[t]) atomicAdd(&cnt1[t], h[t]);
    if (h[t + 256]) atomicAdd(&cnt2[t], h[t + 256]);
}

// ---------- scan 512 bucket counts -> slab bases sb[513]; zero cursors ----------
__global__ __launch_bounds__(256) void scan_buckets(const int* __restrict__ cnt,
                                                    int* __restrict__ sb,
                                                    int* __restrict__ gc) {
    __shared__ int buf[256];
    int t = threadIdx.x;
    int v = cnt[t]; buf[t] = v; __syncthreads();
    for (int o = 1; o < 256; o <<= 1) {
        int a = (t >= o) ? buf[t - o] : 0; __syncthreads();
        buf[t] += a; __syncthreads();
    }
    sb[t] = buf[t] - v;               // pass-1 region: [0, NNZ)
    __syncthreads();
    int v2 = cnt[256 + t]; buf[t] = v2; __syncthreads();
    for (int o = 1; o < 256; o <<= 1) {
        int a = (t >= o) ? buf[t - o] : 0; __syncthreads();
        buf[t] += a; __syncthreads();
    }
    sb[256 + t] = NNZ_E + buf[t] - v2;  // pass-2 region: [NNZ, 2*NNZ)
    if (t == 255) sb[512] = 2 * NNZ_E;
    gc[t] = 0; gc[256 + t] = 0;
}

// ---------- fused phase A: bin 2048 edges -> 4096 entries over 512 buckets ----------
__global__ __launch_bounds__(256) void phaseA_fused(const int* __restrict__ rows,
                                                    const int* __restrict__ cols,
                                                    const float* __restrict__ vals,
                                                    const int* __restrict__ slabBase,
                                                    int* __restrict__ gCur,
                                                    uint2* __restrict__ slab) {
    __shared__ uint2 sortedL[2 * EPB2];          // 32 KB
    __shared__ unsigned short bktL[2 * EPB2];    // 8 KB
    __shared__ int cnt[512], off[512], cur[512], gbase[512];   // 8 KB
    __shared__ int part[256];                    // 1 KB
    __shared__ int totE;
    int t = threadIdx.x;
    int base = blockIdx.x * EPB2;
    cnt[t] = 0; cnt[t + 256] = 0;
    __syncthreads();

    uint2 eA[8], eB[8];
    short bA[8], bB[8];
    #pragma unroll
    for (int j = 0; j < 8; j++) {
        int e = base + j * 256 + t;
        if (e < NNZ_E) {
            int r = rows[e], c = cols[e];
            unsigned v = __float_as_uint(vals[e]);
            int b1 = c / DPB, dl1 = c - b1 * DPB;     // pass-1 dest = col, src = row
            int b2 = r / DPB, dl2 = r - b2 * DPB;     // pass-2 dest = row, src = col
            bA[j] = (short)b1;
            eA[j].x = ((unsigned)dl1 << 18) | (unsigned)r;
            eA[j].y = v;
            bB[j] = (short)(256 + b2);
            eB[j].x = ((unsigned)dl2 << 18) | (unsigned)c;
            eB[j].y = v;
            atomicAdd(&cnt[b1], 1);
            atomicAdd(&cnt[256 + b2], 1);
        } else { bA[j] = -1; bB[j] = -1; }
    }
    __syncthreads();
    // scan 512 counts (2 per thread) -> exclusive off/cur
    int c0 = cnt[2 * t], c1 = cnt[2 * t + 1];
    int ps = c0 + c1;
    part[t] = ps; __syncthreads();
    for (int o = 1; o < 256; o <<= 1) {
        int a = (t >= o) ? part[t - o] : 0; __syncthreads();
        part[t] += a; __syncthreads();
    }
    int bs = part[t] - ps;
    off[2 * t] = bs;          cur[2 * t] = bs;
    off[2 * t + 1] = bs + c0; cur[2 * t + 1] = bs + c0;
    if (t == 255) totE = part[255];
    __syncthreads();
    // bucket-sorted scatter into LDS (both entries per edge)
    #pragma unroll
    for (int j = 0; j < 8; j++) {
        if (bA[j] >= 0) {
            int p = atomicAdd(&cur[(int)bA[j]], 1);
            sortedL[p] = eA[j]; bktL[p] = (unsigned short)bA[j];
            p = atomicAdd(&cur[(int)bB[j]], 1);
            sortedL[p] = eB[j]; bktL[p] = (unsigned short)bB[j];
        }
    }
    __syncthreads();
    // reserve global slab space, one atomic per non-empty bucket
    for (int b = t; b < 512; b += 256) {
        int n = cnt[b];
        if (n > 0) gbase[b] = atomicAdd(&gCur[b], n);
    }
    __syncthreads();
    int nE = totE;
    for (int i = t; i < nE; i += 256) {
        int b = bktL[i];
        slab[slabBase[b] + gbase[b] + (i - off[b])] = sortedL[i];
    }
}

// ---------- phase B: per-bucket exact sort + offs write + (src,val) emit ----------
__global__ __launch_bounds__(256) void phaseB(const uint2* __restrict__ slab,
                                              const int* __restrict__ slabBase,
                                              int* __restrict__ offs1,
                                              int* __restrict__ offs2,
                                              uint2* __restrict__ sorted) {
    __shared__ int cnt[DPB], sc[DPB], cur[DPB], part[256];
    int b = blockIdx.x, t = threadIdx.x;
    int sb = slabBase[b], se = slabBase[b + 1];
    int n = se - sb;
    for (int d = t; d < DPB; d += 256) cnt[d] = 0;
    __syncthreads();
    for (int i = t; i < n; i += 256)
        atomicAdd(&cnt[slab[sb + i].x >> 18], 1);
    __syncthreads();
    int d0 = t * 3;
    int c0 = (d0     < DPB) ? cnt[d0]     : 0;
    int c1 = (d0 + 1 < DPB) ? cnt[d0 + 1] : 0;
    int c2 = (d0 + 2 < DPB) ? cnt[d0 + 2] : 0;
    int ps = c0 + c1 + c2;
    part[t] = ps;
    __syncthreads();
    for (int o = 1; o < 256; o <<= 1) {
        int a = (t >= o) ? part[t - o] : 0; __syncthreads();
        part[t] += a; __syncthreads();
    }
    int bs = part[t] - ps;
    if (d0     < DPB) { sc[d0]     = bs;           cur[d0]     = bs; }
    if (d0 + 1 < DPB) { sc[d0 + 1] = bs + c0;      cur[d0 + 1] = bs + c0; }
    if (d0 + 2 < DPB) { sc[d0 + 2] = bs + c0 + c1; cur[d0 + 2] = bs + c0 + c1; }
    __syncthreads();
    int destBase = (b & 255) * DPB;
    int* offs = (b < NBUCK) ? offs1 : offs2;
    for (int d = t; d < DPB; d += 256) {
        int dd = destBase + d;
        if (dd <= N_TOTAL) offs[dd] = sb + sc[d];   // absolute index into sorted[]
    }
    for (int i = t; i < n; i += 256) {
        uint2 e = slab[sb + i];
        int dl = e.x >> 18;
        int p = atomicAdd(&cur[dl], 1);
        sorted[sb + p] = make_uint2(e.x & 0x3FFFF, e.y);
    }
}

// ---------- gather 1: SGPR metadata, saddr gathers, bf16 in/out ----------
__global__ __launch_bounds__(256) void gather1(const uint* __restrict__ srcBf,
                                               const int* __restrict__ offs,
                                               const uint2* __restrict__ edges,
                                               uint* __restrict__ dstBf) {
    int lane = threadIdx.x & 63;
    int row = blockIdx.x * 4 + (threadIdx.x >> 6);      // grid covers exactly N_TOTAL
    int row_u = __builtin_amdgcn_readfirstlane(row);
    uvec2 be;
    sload_be(be, offs + row_u);
    int beg = (int)be[0];
    int n = (int)be[1] - beg;
    const u64* ep = (const u64*)edges + beg;
    uvec16 mA, mB;
    sload_pair(mA, mB, ep);                             // <=128B past array end stays in ws
    float ax = 0.f, ay = 0.f, bx = 0.f, by = 0.f;
    chunk8(mA, n < 8 ? n : 8, lane, srcBf, ax, ay, bx, by);
    if (n > 8) {
        chunk8(mB, n - 8 < 8 ? n - 8 : 8, lane, srcBf, ax, ay, bx, by);
        if (n > 16) {
            uvec16 mC, mD;
            sload_pair(mC, mD, ep + 16);
            chunk8(mC, n - 16 < 8 ? n - 16 : 8, lane, srcBf, ax, ay, bx, by);
            if (n > 24) {
                chunk8(mD, n - 24 < 8 ? n - 24 : 8, lane, srcBf, ax, ay, bx, by);
                for (int k = 32; k < n; k++) {          // statistically never
                    uint2 e = edges[beg + k];
                    float v = __uint_as_float(e.y);
                    float2 u = unpack_bf16(srcBf[(((size_t)e.x) << 6) + lane]);
                    ax += v * u.x; ay += v * u.y;
                }
            }
        }
    }
    dstBf[(size_t)row_u * 64 + lane] = pack_bf16(ax + bx, ay + by);
}

// ---------- gather 2 + LN + residual: SGPR metadata, saddr gathers ----------
__global__ __launch_bounds__(256) void gather2_ln(const uint* __restrict__ hBf,
                                                  const int* __restrict__ offs,
                                                  const uint2* __restrict__ edges,
                                                  const uint* __restrict__ egoBf,
                                                  const float* __restrict__ gamma,
                                                  const float* __restrict__ beta,
                                                  float* __restrict__ out) {
    int lane = threadIdx.x & 63;
    int row = blockIdx.x * 4 + (threadIdx.x >> 6);
    int row_u = __builtin_amdgcn_readfirstlane(row);
    uvec2 be;
    sload_be(be, offs + row_u);
    int beg = (int)be[0];
    int n = (int)be[1] - beg;
    const u64* ep = (const u64*)edges + beg;
    uvec16 mA, mB;
    sload_pair(mA, mB, ep);
    float ax = 0.f, ay = 0.f, bx = 0.f, by = 0.f;
    chunk8(mA, n < 8 ? n : 8, lane, hBf, ax, ay, bx, by);
    if (n > 8) {
        chunk8(mB, n - 8 < 8 ? n - 8 : 8, lane, hBf, ax, ay, bx, by);
        if (n > 16) {
            uvec16 mC, mD;
            sload_pair(mC, mD, ep + 16);
            chunk8(mC, n - 16 < 8 ? n - 16 : 8, lane, hBf, ax, ay, bx, by);
            if (n > 24) {
                chunk8(mD, n - 24 < 8 ? n - 24 : 8, lane, hBf, ax, ay, bx, by);
                for (int k = 32; k < n; k++) {
                    uint2 e = edges[beg + k];
                    float v = __uint_as_float(e.y);
                    float2 u = unpack_bf16(hBf[(((size_t)e.x) << 6) + lane]);
                    ax += v * u.x; ay += v * u.y;
                }
            }
        }
    }
    float2 acc = make_float2(ax + bx, ay + by);
    float s = acc.x + acc.y;
    float sq = acc.x * acc.x + acc.y * acc.y;
    #pragma unroll
    for (int o = 1; o <= 16; o <<= 1) {
        s  += __shfl_xor(s, o, 64);
        sq += __shfl_xor(sq, o, 64);
    }
    // lanes 0 and 32 hold the two half-sums -> finish with scalar readlanes
    float sT  = rdlane_f(s, 0)  + rdlane_f(s, 32);
    float sqT = rdlane_f(sq, 0) + rdlane_f(sq, 32);
    float mu = sT * (1.0f / DIM);
    float var = sqT * (1.0f / DIM) - mu * mu;
    float rs = rsqrtf(var + 1e-5f);
    float2 g  = ((const float2*)gamma)[lane];
    float2 bb = ((const float2*)beta)[lane];
    unsigned egoW = __builtin_nontemporal_load(&egoBf[(size_t)row_u * 64 + lane]);
    float2 e2 = unpack_bf16(egoW);
    float2 o2;
    o2.x = (acc.x - mu) * rs * g.x + bb.x + e2.x;
    o2.y = (acc.y - mu) * rs * g.y + bb.y + e2.y;
    u64 ow = (u64)__float_as_uint(o2.x) | ((u64)__float_as_uint(o2.y) << 32);
    __builtin_nontemporal_store(ow, (u64*)out + (size_t)row_u * 64 + lane);
}

// ---------- fallback: atomic scatter path (ws too small) ----------
__device__ __forceinline__ void atomic_add_f32(float* p, float v) {
    __hip_atomic_fetch_add(p, v, __ATOMIC_RELAXED, __HIP_MEMORY_SCOPE_AGENT);
}
__global__ void scatter_kernel(const float* __restrict__ src, const float* __restrict__ vals,
                               const int* __restrict__ gidx, const int* __restrict__ sidx,
                               float* __restrict__ dst, int nnz) {
    int gid = blockIdx.x * blockDim.x + threadIdx.x;
    int e = gid >> 5, lane = gid & 31;
    if (e >= nnz) return;
    float v = vals[e];
    float4 x = ((const float4*)(src + (size_t)gidx[e] * DIM))[lane];
    float* d = dst + (size_t)sidx[e] * DIM + lane * 4;
    atomic_add_f32(d + 0, v * x.x); atomic_add_f32(d + 1, v * x.y);
    atomic_add_f32(d + 2, v * x.z); atomic_add_f32(d + 3, v * x.w);
}
__global__ void ln_residual_kernel(const float* __restrict__ h2, const float* __restrict__ ego,
                                   const float* __restrict__ gamma, const float* __restrict__ beta,
                                   float* __restrict__ out, int nrows) {
    int gid = blockIdx.x * blockDim.x + threadIdx.x;
    int row = gid >> 6, lane = gid & 63;
    if (row >= nrows) return;
    float2 x = ((const float2*)(h2 + (size_t)row * DIM))[lane];
    float s = x.x + x.y, sq = x.x * x.x + x.y * x.y;
    #pragma unroll
    for (int o = 32; o > 0; o >>= 1) { s += __shfl_xor(s, o, 64); sq += __shfl_xor(sq, o, 64); }
    float mu = s * (1.0f / DIM), var = sq * (1.0f / DIM) - mu * mu;
    float rs = rsqrtf(var + 1e-5f);
    float2 eg = ((const float2*)(ego + (size_t)row * DIM))[lane];
    float2 g = ((const float2*)gamma)[lane], b = ((const float2*)beta)[lane];
    float2 o2;
    o2.x = (x.x - mu) * rs * g.x + b.x + eg.x;
    o2.y = (x.y - mu) * rs * g.y + b.y + eg.y;
    ((float2*)(out + (size_t)row * DIM))[lane] = o2;
}

// ---------- launch ----------
extern "C" void kernel_launch(void* const* d_in, const int* in_sizes, int n_in,
                              void* d_out, int out_size, void* d_ws, size_t ws_size,
                              hipStream_t stream) {
    const float* ego   = (const float*)d_in[0];
    const float* vals  = (const float*)d_in[1];
    const float* gamma = (const float*)d_in[2];
    const float* beta  = (const float*)d_in[3];
    const int*   rows  = (const int*)d_in[4];
    const int*   cols  = (const int*)d_in[5];
    float* out = (float*)d_out;

    const size_t EGO_BF_B = (size_t)N_TOTAL * DIM * 2;               // 38.4 MB
    const size_t SLAB_B   = (size_t)2 * NNZ_E * sizeof(uint2);       // 24 MB
    const size_t H_BF_B   = (size_t)N_TOTAL * DIM * 2;               // 38.4 MB
    const size_t REGION_B = (SLAB_B > H_BF_B) ? SLAB_B : H_BF_B;     // hBf aliases dead slab
    const size_t SORT_B   = (size_t)2 * NNZ_E * sizeof(uint2);       // 24 MB
    const size_t OFFS_B   = ((size_t)N_TOTAL + 16) * sizeof(int);    // ~0.6 MB each
    const size_t SMALL    = 16384;
    const size_t REQ = EGO_BF_B + REGION_B + SORT_B + 2 * OFFS_B + SMALL;   // ~102 MB
    const size_t H_FP32_B = (size_t)N_TOTAL * DIM * sizeof(float);   // fallback: 76.8 MB

    char* w = (char*)d_ws;
    uint* egoBf   = (uint*)w;   w += EGO_BF_B;
    char* region  = w;          w += REGION_B;
    uint2* slab   = (uint2*)region;      // live: phaseA_fused -> phaseB
    uint* hBf     = (uint*)region;       // live: gather1 -> gather2 (slab dead by then)
    uint2* sorted = (uint2*)w;  w += SORT_B;
    int* offs1    = (int*)w;    w += OFFS_B;
    int* offs2    = (int*)w;    w += OFFS_B;
    int* cntArr   = (int*)w;    w += 512 * sizeof(int);
    int* sb       = (int*)w;    w += 516 * sizeof(int);
    int* gc       = (int*)w;    w += 512 * sizeof(int);

    if (ws_size >= REQ) {
        (void)hipMemsetAsync(cntArr, 0, 512 * sizeof(int), stream);
        conv_bf16<<<(N_TOTAL * DIM / 8) / 256, 256, 0, stream>>>(ego, egoBf);
        coarse_hist<<<512, 256, 0, stream>>>(rows, cols, cntArr, cntArr + 256);
        scan_buckets<<<1, 256, 0, stream>>>(cntArr, sb, gc);
        phaseA_fused<<<A2_BLOCKS, 256, 0, stream>>>(rows, cols, vals, sb, gc, slab);
        phaseB<<<512, 256, 0, stream>>>(slab, sb, offs1, offs2, sorted);

        int ggrid = (N_TOTAL + 3) / 4;      // 4 waves/block, 1 row/wave -> 37500
        gather1<<<ggrid, 256, 0, stream>>>(egoBf, offs1, sorted, hBf);
        gather2_ln<<<ggrid, 256, 0, stream>>>(hBf, offs2, sorted, egoBf, gamma, beta, out);
    } else {
        float* h = (float*)d_ws;            // fallback: fp32 h at ws start
        (void)hipMemsetAsync(h, 0, H_FP32_B, stream);
        (void)hipMemsetAsync(out, 0, H_FP32_B, stream);
        long total = (long)NNZ_E * 32;
        int grid = (int)((total + 255) / 256);
        scatter_kernel<<<grid, 256, 0, stream>>>(ego, vals, rows, cols, h, NNZ_E);
        scatter_kernel<<<grid, 256, 0, stream>>>(h, vals, cols, rows, out, NNZ_E);
        int lngrid = (N_TOTAL * 64 + 255) / 256;
        ln_residual_kernel<<<lngrid, 256, 0, stream>>>(out, ego, gamma, beta, out, N_TOTAL);
    }
}